// Round 1
// baseline (3433.657 us; speedup 1.0000x reference)
//
#include <hip/hip_runtime.h>
#include <stdint.h>

#define cN0 100000
#define cN1 150000
#define cN2 50000
#define cNNZ00 1600000
#define cNNZ12 200000
#define cD 128

__device__ __forceinline__ uint16_t f2bf(float f) {
    uint32_t u = __float_as_uint(f);
    u += 0x7fffu + ((u >> 16) & 1u);
    return (uint16_t)(u >> 16);
}
__device__ __forceinline__ float bf2f(uint32_t lo16) {
    return __uint_as_float(lo16 << 16);
}

// h[r][c] = sum_k relu(x[r][k]) * W[k][c], stored bf16. Optionally writes relu(x) out.
template<int WRITE_RELU>
__global__ __launch_bounds__(256) void gemm_relu_kernel(
    const float* __restrict__ x, const float* __restrict__ W,
    uint16_t* __restrict__ h, float* __restrict__ relu_out, int nrows)
{
    __shared__ float Wl[cD * cD];   // 64 KB
    __shared__ float Xl[32 * cD];   // 16 KB
    const int tid = threadIdx.x;

    // stage W (16384 floats, 64/thread as float4)
    for (int i = tid * 4; i < cD * cD; i += 256 * 4)
        *(float4*)&Wl[i] = *(const float4*)&W[i];

    const int row0 = blockIdx.x * 32;
    // stage 32 rows of x with relu; optionally write relu(x) to global
    for (int i = tid; i < 32 * cD / 4; i += 256) {
        int off = i * 4;
        int r = row0 + (off >> 7);
        float4 v = make_float4(0.f, 0.f, 0.f, 0.f);
        if (r < nrows) {
            v = *(const float4*)&x[(size_t)row0 * cD + off];
            v.x = fmaxf(v.x, 0.f); v.y = fmaxf(v.y, 0.f);
            v.z = fmaxf(v.z, 0.f); v.w = fmaxf(v.w, 0.f);
            if (WRITE_RELU)
                *(float4*)&relu_out[(size_t)row0 * cD + off] = v;
        }
        *(float4*)&Xl[off] = v;
    }
    __syncthreads();

    const int g = tid >> 5;   // row group (4 rows each, 8 groups)
    const int l = tid & 31;   // col group (4 cols each)
    float4 acc[4];
    #pragma unroll
    for (int j = 0; j < 4; ++j) acc[j] = make_float4(0.f, 0.f, 0.f, 0.f);

    #pragma unroll 4
    for (int k = 0; k < cD; ++k) {
        float4 w4 = *(float4*)&Wl[k * cD + l * 4];
        #pragma unroll
        for (int j = 0; j < 4; ++j) {
            float xv = Xl[(g * 4 + j) * cD + k];
            acc[j].x = fmaf(xv, w4.x, acc[j].x);
            acc[j].y = fmaf(xv, w4.y, acc[j].y);
            acc[j].z = fmaf(xv, w4.z, acc[j].z);
            acc[j].w = fmaf(xv, w4.w, acc[j].w);
        }
    }

    #pragma unroll
    for (int j = 0; j < 4; ++j) {
        int r = row0 + g * 4 + j;
        if (r < nrows) {
            ushort4 s;
            s.x = f2bf(acc[j].x); s.y = f2bf(acc[j].y);
            s.z = f2bf(acc[j].z); s.w = f2bf(acc[j].w);
            *(ushort4*)&h[(size_t)r * cD + l * 4] = s;
        }
    }
}

// y[rows[e]] += vals[e] * h[cols[e]] ; 32 lanes per edge, 4 elems/lane
__global__ __launch_bounds__(256) void scatter_kernel(
    const int* __restrict__ rows, const int* __restrict__ cols,
    const float* __restrict__ vals, const uint16_t* __restrict__ h,
    float* __restrict__ y, int nnz)
{
    int idx = blockIdx.x * 256 + threadIdx.x;
    int e = idx >> 5;
    if (e >= nnz) return;
    int l = idx & 31;
    int r = rows[e];
    int c = cols[e];
    float v = vals[e];
    const uint2 hp = *(const uint2*)&h[(size_t)c * cD + l * 4];
    float* yp = &y[(size_t)r * cD + l * 4];
    atomicAdd(yp + 0, v * bf2f(hp.x & 0xffffu));
    atomicAdd(yp + 1, v * bf2f(hp.x >> 16));
    atomicAdd(yp + 2, v * bf2f(hp.y & 0xffffu));
    atomicAdd(yp + 3, v * bf2f(hp.y >> 16));
}

__global__ __launch_bounds__(256) void relu_two_regions(
    float* __restrict__ y0, float* __restrict__ y2, int n0, int n2)
{
    int total4 = (n0 + n2) >> 2;
    for (int i = blockIdx.x * blockDim.x + threadIdx.x; i < total4;
         i += gridDim.x * blockDim.x) {
        float* base;
        int off = i << 2;
        if (off < n0) { base = y0; }
        else          { base = y2; off -= n0; }
        float4 v = *(float4*)&base[off];
        v.x = fmaxf(v.x, 0.f); v.y = fmaxf(v.y, 0.f);
        v.z = fmaxf(v.z, 0.f); v.w = fmaxf(v.w, 0.f);
        *(float4*)&base[off] = v;
    }
}

extern "C" void kernel_launch(void* const* d_in, const int* in_sizes, int n_in,
                              void* d_out, int out_size, void* d_ws, size_t ws_size,
                              hipStream_t stream) {
    const float* x0  = (const float*)d_in[0];
    const float* x1  = (const float*)d_in[1];
    const int*   r00 = (const int*)d_in[2];
    const int*   c00 = (const int*)d_in[3];
    const float* v00 = (const float*)d_in[4];
    const int*   r12 = (const int*)d_in[5];
    const int*   c12 = (const int*)d_in[6];
    const float* v12 = (const float*)d_in[7];
    const float* W0  = (const float*)d_in[8];
    const float* W12 = (const float*)d_in[9];

    float* out  = (float*)d_out;
    float* y0   = out;                                  // [N0,128]
    float* out1 = out + (size_t)cN0 * cD;               // relu(x1) [N1,128]
    float* y2   = out + (size_t)(cN0 + cN1) * cD;       // [N2,128]

    uint16_t* h0  = (uint16_t*)d_ws;                    // 25.6 MB bf16
    uint16_t* h12 = h0 + (size_t)cN0 * cD;              // 38.4 MB bf16

    // zero accumulation targets (d_out is poisoned before every launch)
    hipMemsetAsync(y0, 0, (size_t)cN0 * cD * sizeof(float), stream);
    hipMemsetAsync(y2, 0, (size_t)cN2 * cD * sizeof(float), stream);

    gemm_relu_kernel<0><<<(cN0 + 31) / 32, 256, 0, stream>>>(x0, W0, h0, nullptr, cN0);
    gemm_relu_kernel<1><<<(cN1 + 31) / 32, 256, 0, stream>>>(x1, W12, h12, out1, cN1);

    scatter_kernel<<<(cNNZ00 * 32) / 256, 256, 0, stream>>>(r00, c00, v00, h0, y0, cNNZ00);
    scatter_kernel<<<(cNNZ12 * 32) / 256, 256, 0, stream>>>(r12, c12, v12, h12, y2, cNNZ12);

    relu_two_regions<<<2048, 256, 0, stream>>>(y0, y2, cN0 * cD, cN2 * cD);
}

// Round 2
// 692.911 us; speedup vs baseline: 4.9554x; 4.9554x over previous
//
#include <hip/hip_runtime.h>
#include <stdint.h>

#define cN0 100000
#define cN1 150000
#define cN2 50000
#define cNNZ00 1600000
#define cNNZ12 200000
#define cD 128

__device__ __forceinline__ uint16_t f2bf(float f) {
    uint32_t u = __float_as_uint(f);
    u += 0x7fffu + ((u >> 16) & 1u);
    return (uint16_t)(u >> 16);
}
__device__ __forceinline__ float bf2f(uint32_t lo16) {
    return __uint_as_float(lo16 << 16);
}

// ---------------- GEMM: h[r][c] = sum_k relu(x[r][k]) * W[k][c] (bf16 out) ----
template<int WRITE_RELU>
__global__ __launch_bounds__(256) void gemm_relu_kernel(
    const float* __restrict__ x, const float* __restrict__ W,
    uint16_t* __restrict__ h, float* __restrict__ relu_out, int nrows)
{
    __shared__ float Wl[cD * cD];   // 64 KB
    __shared__ float Xl[32 * cD];   // 16 KB
    const int tid = threadIdx.x;

    for (int i = tid * 4; i < cD * cD; i += 256 * 4)
        *(float4*)&Wl[i] = *(const float4*)&W[i];

    const int row0 = blockIdx.x * 32;
    for (int i = tid; i < 32 * cD / 4; i += 256) {
        int off = i * 4;
        int r = row0 + (off >> 7);
        float4 v = make_float4(0.f, 0.f, 0.f, 0.f);
        if (r < nrows) {
            v = *(const float4*)&x[(size_t)row0 * cD + off];
            v.x = fmaxf(v.x, 0.f); v.y = fmaxf(v.y, 0.f);
            v.z = fmaxf(v.z, 0.f); v.w = fmaxf(v.w, 0.f);
            if (WRITE_RELU)
                *(float4*)&relu_out[(size_t)row0 * cD + off] = v;
        }
        *(float4*)&Xl[off] = v;
    }
    __syncthreads();

    const int g = tid >> 5;
    const int l = tid & 31;
    float4 acc[4];
    #pragma unroll
    for (int j = 0; j < 4; ++j) acc[j] = make_float4(0.f, 0.f, 0.f, 0.f);

    #pragma unroll 4
    for (int k = 0; k < cD; ++k) {
        float4 w4 = *(float4*)&Wl[k * cD + l * 4];
        #pragma unroll
        for (int j = 0; j < 4; ++j) {
            float xv = Xl[(g * 4 + j) * cD + k];
            acc[j].x = fmaf(xv, w4.x, acc[j].x);
            acc[j].y = fmaf(xv, w4.y, acc[j].y);
            acc[j].z = fmaf(xv, w4.z, acc[j].z);
            acc[j].w = fmaf(xv, w4.w, acc[j].w);
        }
    }

    #pragma unroll
    for (int j = 0; j < 4; ++j) {
        int r = row0 + g * 4 + j;
        if (r < nrows) {
            ushort4 s;
            s.x = f2bf(acc[j].x); s.y = f2bf(acc[j].y);
            s.z = f2bf(acc[j].z); s.w = f2bf(acc[j].w);
            *(ushort4*)&h[(size_t)r * cD + l * 4] = s;
        }
    }
}

// ---------------- CSR build ----------------
__global__ __launch_bounds__(256) void hist_kernel(
    const int* __restrict__ rows, int nnz, int* __restrict__ cnt)
{
    int e = blockIdx.x * 256 + threadIdx.x;
    if (e < nnz) atomicAdd(&cnt[rows[e]], 1);
}

// phase 1: per-block (1024-elem chunk) sums
__global__ __launch_bounds__(256) void scan_partial(
    const int* __restrict__ cnt, int n, int* __restrict__ partial)
{
    int t = threadIdx.x;
    int idx = blockIdx.x * 1024 + t * 4;
    int s = 0;
    #pragma unroll
    for (int k = 0; k < 4; ++k)
        if (idx + k < n) s += cnt[idx + k];
    __shared__ int sm[256];
    sm[t] = s;
    __syncthreads();
    for (int o = 128; o > 0; o >>= 1) {
        if (t < o) sm[t] += sm[t + o];
        __syncthreads();
    }
    if (t == 0) partial[blockIdx.x] = sm[0];
}

// phase 2: exclusive scan of partials (nb <= 128), single block
__global__ __launch_bounds__(256) void scan_small(int* __restrict__ partial, int nb)
{
    __shared__ int sm[128];
    int t = threadIdx.x;
    if (t < nb) sm[t] = partial[t];
    __syncthreads();
    if (t == 0) {
        int run = 0;
        for (int i = 0; i < nb; ++i) { int v = sm[i]; sm[i] = run; run += v; }
    }
    __syncthreads();
    if (t < nb) partial[t] = sm[t];
}

// phase 3: final exclusive scan; writes row_start and cursor (cursor may alias cnt)
__global__ __launch_bounds__(256) void scan_final(
    const int* __restrict__ cnt, int n, const int* __restrict__ partial,
    int* __restrict__ row_start, int* __restrict__ cursor, int nnz)
{
    int t = threadIdx.x;
    int idx = blockIdx.x * 1024 + t * 4;
    int c[4];
    #pragma unroll
    for (int k = 0; k < 4; ++k)
        c[k] = (idx + k < n) ? cnt[idx + k] : 0;
    int s = c[0] + c[1] + c[2] + c[3];
    __shared__ int sm[256];
    sm[t] = s;
    __syncthreads();
    for (int o = 1; o < 256; o <<= 1) {
        int v = (t >= o) ? sm[t - o] : 0;
        __syncthreads();
        sm[t] += v;
        __syncthreads();
    }
    int off = partial[blockIdx.x] + sm[t] - s;   // exclusive prefix for this thread
    #pragma unroll
    for (int k = 0; k < 4; ++k) {
        if (idx + k < n) {
            row_start[idx + k] = off;
            cursor[idx + k]   = off;
            off += c[k];
        }
    }
    if (blockIdx.x == 0 && t == 0) row_start[n] = nnz;
}

__global__ __launch_bounds__(256) void place_kernel(
    const int* __restrict__ rows, const int* __restrict__ cols,
    const float* __restrict__ vals, int nnz, int* __restrict__ cursor,
    int* __restrict__ scol, float* __restrict__ sval)
{
    int e = blockIdx.x * 256 + threadIdx.x;
    if (e >= nnz) return;
    int pos = atomicAdd(&cursor[rows[e]], 1);
    scol[pos] = cols[e];
    sval[pos] = vals[e];
}

// ---------------- Pull: y[r] = relu(sum_e val*h[col]) , one wave per row -----
__global__ __launch_bounds__(256) void pull_kernel(
    const int* __restrict__ row_start, const int* __restrict__ scol,
    const float* __restrict__ sval, const uint16_t* __restrict__ h,
    float* __restrict__ y, int nrows)
{
    int w = (blockIdx.x * 256 + threadIdx.x) >> 6;  // row = global wave id
    int l = threadIdx.x & 63;                       // lane: features 2l, 2l+1
    if (w >= nrows) return;
    int s = row_start[w], e = row_start[w + 1];
    float a0 = 0.f, a1 = 0.f;
    int i = s;
    for (; i + 3 < e; i += 4) {
        int   c0 = scol[i],     c1 = scol[i + 1], c2 = scol[i + 2], c3 = scol[i + 3];
        float v0 = sval[i],     v1 = sval[i + 1], v2 = sval[i + 2], v3 = sval[i + 3];
        uint32_t p0 = *(const uint32_t*)&h[(size_t)c0 * cD + l * 2];
        uint32_t p1 = *(const uint32_t*)&h[(size_t)c1 * cD + l * 2];
        uint32_t p2 = *(const uint32_t*)&h[(size_t)c2 * cD + l * 2];
        uint32_t p3 = *(const uint32_t*)&h[(size_t)c3 * cD + l * 2];
        a0 = fmaf(v0, bf2f(p0 & 0xffffu), a0); a1 = fmaf(v0, bf2f(p0 >> 16), a1);
        a0 = fmaf(v1, bf2f(p1 & 0xffffu), a0); a1 = fmaf(v1, bf2f(p1 >> 16), a1);
        a0 = fmaf(v2, bf2f(p2 & 0xffffu), a0); a1 = fmaf(v2, bf2f(p2 >> 16), a1);
        a0 = fmaf(v3, bf2f(p3 & 0xffffu), a0); a1 = fmaf(v3, bf2f(p3 >> 16), a1);
    }
    for (; i < e; ++i) {
        int c = scol[i]; float v = sval[i];
        uint32_t p = *(const uint32_t*)&h[(size_t)c * cD + l * 2];
        a0 = fmaf(v, bf2f(p & 0xffffu), a0);
        a1 = fmaf(v, bf2f(p >> 16), a1);
    }
    *(float2*)&y[(size_t)w * cD + l * 2] = make_float2(fmaxf(a0, 0.f), fmaxf(a1, 0.f));
}

extern "C" void kernel_launch(void* const* d_in, const int* in_sizes, int n_in,
                              void* d_out, int out_size, void* d_ws, size_t ws_size,
                              hipStream_t stream) {
    const float* x0  = (const float*)d_in[0];
    const float* x1  = (const float*)d_in[1];
    const int*   r00 = (const int*)d_in[2];
    const int*   c00 = (const int*)d_in[3];
    const float* v00 = (const float*)d_in[4];
    const int*   r12 = (const int*)d_in[5];
    const int*   c12 = (const int*)d_in[6];
    const float* v12 = (const float*)d_in[7];
    const float* W0  = (const float*)d_in[8];
    const float* W12 = (const float*)d_in[9];

    float* out  = (float*)d_out;
    float* y0   = out;                                  // [N0,128]
    float* out1 = out + (size_t)cN0 * cD;               // relu(x1) [N1,128]
    float* y2   = out + (size_t)(cN0 + cN1) * cD;       // [N2,128]

    // h12 staged in the y0 region of d_out (38.4 MB <= 51.2 MB); consumed by
    // pull(y2) before pull(y0) overwrites the region (stream-ordered).
    uint16_t* h12 = (uint16_t*)y0;

    // ws layout (41.4 MB)
    char* ws = (char*)d_ws;
    size_t o = 0;
    uint16_t* h0      = (uint16_t*)(ws + o); o += (size_t)cN0 * cD * 2;   // 25.6 MB
    int*      scol00  = (int*)     (ws + o); o += (size_t)cNNZ00 * 4;     // 6.4 MB
    float*    sval00  = (float*)   (ws + o); o += (size_t)cNNZ00 * 4;     // 6.4 MB
    int*      scol12  = (int*)     (ws + o); o += (size_t)cNNZ12 * 4;     // 0.8 MB
    float*    sval12  = (float*)   (ws + o); o += (size_t)cNNZ12 * 4;     // 0.8 MB
    int*      rs0     = (int*)     (ws + o); o += 400016;                 // row_start0 [N0+1]
    int*      cur0    = (int*)     (ws + o); o += 400000;                 // cursor0/cnt0
    int*      rs2     = (int*)     (ws + o); o += 200016;                 // row_start2 [N2+1]
    int*      cur2    = (int*)     (ws + o); o += 200000;                 // cursor2/cnt2
    int*      part0   = (int*)     (ws + o); o += 512;
    int*      part2   = (int*)     (ws + o); o += 512;

    const int nb0 = (cN0 + 1023) / 1024;   // 98
    const int nb2 = (cN2 + 1023) / 1024;   // 49

    // ---- graph 1->2 path: gemm12 -> CSR12 -> pull y2 (reads h12 in y0 region)
    gemm_relu_kernel<1><<<(cN1 + 31) / 32, 256, 0, stream>>>(x1, W12, h12, out1, cN1);

    hipMemsetAsync(cur2, 0, (size_t)cN2 * 4, stream);
    hist_kernel<<<(cNNZ12 + 255) / 256, 256, 0, stream>>>(r12, cNNZ12, cur2);
    scan_partial<<<nb2, 256, 0, stream>>>(cur2, cN2, part2);
    scan_small<<<1, 256, 0, stream>>>(part2, nb2);
    scan_final<<<nb2, 256, 0, stream>>>(cur2, cN2, part2, rs2, cur2, cNNZ12);
    place_kernel<<<(cNNZ12 + 255) / 256, 256, 0, stream>>>(r12, c12, v12, cNNZ12, cur2, scol12, sval12);
    pull_kernel<<<(cN2 + 3) / 4, 256, 0, stream>>>(rs2, scol12, sval12, h12, y2, cN2);

    // ---- graph 0->0 path: gemm0 -> CSR00 -> pull y0 (overwrites h12 region)
    gemm_relu_kernel<0><<<(cN0 + 31) / 32, 256, 0, stream>>>(x0, W0, h0, nullptr, cN0);

    hipMemsetAsync(cur0, 0, (size_t)cN0 * 4, stream);
    hist_kernel<<<(cNNZ00 + 255) / 256, 256, 0, stream>>>(r00, cNNZ00, cur0);
    scan_partial<<<nb0, 256, 0, stream>>>(cur0, cN0, part0);
    scan_small<<<1, 256, 0, stream>>>(part0, nb0);
    scan_final<<<nb0, 256, 0, stream>>>(cur0, cN0, part0, rs0, cur0, cNNZ00);
    place_kernel<<<(cNNZ00 + 255) / 256, 256, 0, stream>>>(r00, c00, v00, cNNZ00, cur0, scol00, sval00);
    pull_kernel<<<(cN0 + 3) / 4, 256, 0, stream>>>(rs0, scol00, sval00, h0, y0, cN0);
}

// Round 3
// 623.324 us; speedup vs baseline: 5.5086x; 1.1116x over previous
//
#include <hip/hip_runtime.h>
#include <stdint.h>

#define cN0 100000
#define cN1 150000
#define cN2 50000
#define cNNZ00 1600000
#define cNNZ12 200000
#define cD 128

typedef __attribute__((ext_vector_type(8))) short short8;
typedef __attribute__((ext_vector_type(4))) float f32x4;

__device__ __forceinline__ uint16_t f2bf(float f) {
    uint32_t u = __float_as_uint(f);
    u += 0x7fffu + ((u >> 16) & 1u);
    return (uint16_t)(u >> 16);
}
__device__ __forceinline__ float bf2f(uint32_t lo16) {
    return __uint_as_float(lo16 << 16);
}

// ---------------- MFMA GEMM: h[r][c] = bf16( sum_k relu(x[r][k]) * W[k][c] ) --
// Block: 256 thr = 4 waves, 128 rows. W in LDS fragment-packed: [kt][ct][lane][8].
template<int WRITE_RELU>
__global__ __launch_bounds__(256) void gemm_mfma_kernel(
    const float* __restrict__ x, const float* __restrict__ W,
    uint16_t* __restrict__ h, float* __restrict__ relu_out, int nrows)
{
    __shared__ __align__(16) uint16_t Bpack[cD * cD];   // 32 KB

    const int tid = threadIdx.x;
    // stage W: coalesced float4 reads, scatter bf16 into packed layout (~2-way conflicts)
    for (int i = tid * 4; i < cD * cD; i += 1024) {
        int k = i >> 7, c = i & 127;
        float4 w = *(const float4*)&W[i];
        int kt = k >> 5, q = (k >> 3) & 3, j = k & 7;
        uint16_t b[4] = { f2bf(w.x), f2bf(w.y), f2bf(w.z), f2bf(w.w) };
        #pragma unroll
        for (int t = 0; t < 4; ++t) {
            int cc = c + t, ct = cc >> 4, n = cc & 15;
            Bpack[(((kt * 8 + ct) * 64) + q * 16 + n) * 8 + j] = b[t];
        }
    }
    __syncthreads();

    const int wid = tid >> 6, l = tid & 63;
    const int rb = blockIdx.x * 128 + wid * 32;
    const int m = l & 15, q = l >> 4;
    const int r0 = rb + m, r1 = rb + 16 + m;

    f32x4 acc[2][8];
    #pragma unroll
    for (int rt = 0; rt < 2; ++rt)
        #pragma unroll
        for (int ct = 0; ct < 8; ++ct)
            acc[rt][ct] = (f32x4){0.f, 0.f, 0.f, 0.f};

    for (int kt = 0; kt < 4; ++kt) {
        const int k0 = kt * 32 + q * 8;
        float4 xa0 = make_float4(0.f,0.f,0.f,0.f), xa1 = xa0;
        float4 xb0 = xa0, xb1 = xa0;
        if (r0 < nrows) {
            xa0 = *(const float4*)&x[(size_t)r0 * cD + k0];
            xa1 = *(const float4*)&x[(size_t)r0 * cD + k0 + 4];
        }
        if (r1 < nrows) {
            xb0 = *(const float4*)&x[(size_t)r1 * cD + k0];
            xb1 = *(const float4*)&x[(size_t)r1 * cD + k0 + 4];
        }
        xa0.x=fmaxf(xa0.x,0.f); xa0.y=fmaxf(xa0.y,0.f); xa0.z=fmaxf(xa0.z,0.f); xa0.w=fmaxf(xa0.w,0.f);
        xa1.x=fmaxf(xa1.x,0.f); xa1.y=fmaxf(xa1.y,0.f); xa1.z=fmaxf(xa1.z,0.f); xa1.w=fmaxf(xa1.w,0.f);
        xb0.x=fmaxf(xb0.x,0.f); xb0.y=fmaxf(xb0.y,0.f); xb0.z=fmaxf(xb0.z,0.f); xb0.w=fmaxf(xb0.w,0.f);
        xb1.x=fmaxf(xb1.x,0.f); xb1.y=fmaxf(xb1.y,0.f); xb1.z=fmaxf(xb1.z,0.f); xb1.w=fmaxf(xb1.w,0.f);
        if (WRITE_RELU) {
            if (r0 < nrows) {
                *(float4*)&relu_out[(size_t)r0 * cD + k0]     = xa0;
                *(float4*)&relu_out[(size_t)r0 * cD + k0 + 4] = xa1;
            }
            if (r1 < nrows) {
                *(float4*)&relu_out[(size_t)r1 * cD + k0]     = xb0;
                *(float4*)&relu_out[(size_t)r1 * cD + k0 + 4] = xb1;
            }
        }
        short8 a0, a1;
        a0[0]=(short)f2bf(xa0.x); a0[1]=(short)f2bf(xa0.y); a0[2]=(short)f2bf(xa0.z); a0[3]=(short)f2bf(xa0.w);
        a0[4]=(short)f2bf(xa1.x); a0[5]=(short)f2bf(xa1.y); a0[6]=(short)f2bf(xa1.z); a0[7]=(short)f2bf(xa1.w);
        a1[0]=(short)f2bf(xb0.x); a1[1]=(short)f2bf(xb0.y); a1[2]=(short)f2bf(xb0.z); a1[3]=(short)f2bf(xb0.w);
        a1[4]=(short)f2bf(xb1.x); a1[5]=(short)f2bf(xb1.y); a1[6]=(short)f2bf(xb1.z); a1[7]=(short)f2bf(xb1.w);

        #pragma unroll
        for (int ct = 0; ct < 8; ++ct) {
            short8 bf = *(const short8*)&Bpack[((kt * 8 + ct) * 64 + l) * 8];
            acc[0][ct] = __builtin_amdgcn_mfma_f32_16x16x32_bf16(a0, bf, acc[0][ct], 0, 0, 0);
            acc[1][ct] = __builtin_amdgcn_mfma_f32_16x16x32_bf16(a1, bf, acc[1][ct], 0, 0, 0);
        }
    }

    // C/D: col = l&15, row = q*4 + reg
    #pragma unroll
    for (int rt = 0; rt < 2; ++rt) {
        #pragma unroll
        for (int i = 0; i < 4; ++i) {
            int row = rb + rt * 16 + q * 4 + i;
            if (row < nrows) {
                #pragma unroll
                for (int ct = 0; ct < 8; ++ct)
                    h[(size_t)row * cD + ct * 16 + m] = f2bf(acc[rt][ct][i]);
            }
        }
    }
}

// ---------------- CSR build ----------------
__global__ __launch_bounds__(256) void hist_kernel(
    const int* __restrict__ rows, int nnz, int* __restrict__ cnt)
{
    int e = blockIdx.x * 256 + threadIdx.x;
    if (e < nnz) atomicAdd(&cnt[rows[e]], 1);
}

__global__ __launch_bounds__(256) void scan_partial(
    const int* __restrict__ cnt, int n, int* __restrict__ partial)
{
    int t = threadIdx.x;
    int idx = blockIdx.x * 1024 + t * 4;
    int s = 0;
    #pragma unroll
    for (int k = 0; k < 4; ++k)
        if (idx + k < n) s += cnt[idx + k];
    __shared__ int sm[256];
    sm[t] = s;
    __syncthreads();
    for (int o = 128; o > 0; o >>= 1) {
        if (t < o) sm[t] += sm[t + o];
        __syncthreads();
    }
    if (t == 0) partial[blockIdx.x] = sm[0];
}

__global__ __launch_bounds__(256) void scan_small(int* __restrict__ partial, int nb)
{
    __shared__ int sm[128];
    int t = threadIdx.x;
    if (t < nb) sm[t] = partial[t];
    __syncthreads();
    if (t == 0) {
        int run = 0;
        for (int i = 0; i < nb; ++i) { int v = sm[i]; sm[i] = run; run += v; }
    }
    __syncthreads();
    if (t < nb) partial[t] = sm[t];
}

__global__ __launch_bounds__(256) void scan_final(
    const int* __restrict__ cnt, int n, const int* __restrict__ partial,
    int* __restrict__ row_start, int* __restrict__ cursor, int nnz)
{
    int t = threadIdx.x;
    int idx = blockIdx.x * 1024 + t * 4;
    int c[4];
    #pragma unroll
    for (int k = 0; k < 4; ++k)
        c[k] = (idx + k < n) ? cnt[idx + k] : 0;
    int s = c[0] + c[1] + c[2] + c[3];
    __shared__ int sm[256];
    sm[t] = s;
    __syncthreads();
    for (int o = 1; o < 256; o <<= 1) {
        int v = (t >= o) ? sm[t - o] : 0;
        __syncthreads();
        sm[t] += v;
        __syncthreads();
    }
    int off = partial[blockIdx.x] + sm[t] - s;
    #pragma unroll
    for (int k = 0; k < 4; ++k) {
        if (idx + k < n) {
            row_start[idx + k] = off;
            cursor[idx + k]   = off;
            off += c[k];
        }
    }
    if (blockIdx.x == 0 && t == 0) row_start[n] = nnz;
}

__global__ __launch_bounds__(256) void place_kernel(
    const int* __restrict__ rows, const int* __restrict__ cols,
    const float* __restrict__ vals, int nnz, int* __restrict__ cursor,
    uint2* __restrict__ edges)
{
    int e = blockIdx.x * 256 + threadIdx.x;
    if (e >= nnz) return;
    int pos = atomicAdd(&cursor[rows[e]], 1);
    edges[pos] = make_uint2((uint32_t)cols[e], __float_as_uint(vals[e]));
}

// ---------------- Pull: y[r] = relu(sum_e val*h[col]) , one wave per row -----
__global__ __launch_bounds__(256) void pull_kernel(
    const int* __restrict__ row_start, const uint2* __restrict__ edges,
    const uint16_t* __restrict__ h, float* __restrict__ y, int nrows)
{
    int w = (blockIdx.x * 256 + threadIdx.x) >> 6;
    int l = threadIdx.x & 63;
    if (w >= nrows) return;
    int s = row_start[w], e = row_start[w + 1];
    float a0 = 0.f, a1 = 0.f;
    int i = s;
    for (; i + 3 < e; i += 4) {
        uint2 e0 = edges[i], e1 = edges[i + 1], e2 = edges[i + 2], e3 = edges[i + 3];
        uint32_t p0 = *(const uint32_t*)&h[(size_t)e0.x * cD + l * 2];
        uint32_t p1 = *(const uint32_t*)&h[(size_t)e1.x * cD + l * 2];
        uint32_t p2 = *(const uint32_t*)&h[(size_t)e2.x * cD + l * 2];
        uint32_t p3 = *(const uint32_t*)&h[(size_t)e3.x * cD + l * 2];
        float v0 = __uint_as_float(e0.y), v1 = __uint_as_float(e1.y);
        float v2 = __uint_as_float(e2.y), v3 = __uint_as_float(e3.y);
        a0 = fmaf(v0, bf2f(p0 & 0xffffu), a0); a1 = fmaf(v0, bf2f(p0 >> 16), a1);
        a0 = fmaf(v1, bf2f(p1 & 0xffffu), a0); a1 = fmaf(v1, bf2f(p1 >> 16), a1);
        a0 = fmaf(v2, bf2f(p2 & 0xffffu), a0); a1 = fmaf(v2, bf2f(p2 >> 16), a1);
        a0 = fmaf(v3, bf2f(p3 & 0xffffu), a0); a1 = fmaf(v3, bf2f(p3 >> 16), a1);
    }
    for (; i < e; ++i) {
        uint2 ed = edges[i];
        uint32_t p = *(const uint32_t*)&h[(size_t)ed.x * cD + l * 2];
        float v = __uint_as_float(ed.y);
        a0 = fmaf(v, bf2f(p & 0xffffu), a0);
        a1 = fmaf(v, bf2f(p >> 16), a1);
    }
    *(float2*)&y[(size_t)w * cD + l * 2] = make_float2(fmaxf(a0, 0.f), fmaxf(a1, 0.f));
}

extern "C" void kernel_launch(void* const* d_in, const int* in_sizes, int n_in,
                              void* d_out, int out_size, void* d_ws, size_t ws_size,
                              hipStream_t stream) {
    const float* x0  = (const float*)d_in[0];
    const float* x1  = (const float*)d_in[1];
    const int*   r00 = (const int*)d_in[2];
    const int*   c00 = (const int*)d_in[3];
    const float* v00 = (const float*)d_in[4];
    const int*   r12 = (const int*)d_in[5];
    const int*   c12 = (const int*)d_in[6];
    const float* v12 = (const float*)d_in[7];
    const float* W0  = (const float*)d_in[8];
    const float* W12 = (const float*)d_in[9];

    float* out  = (float*)d_out;
    float* y0   = out;
    float* out1 = out + (size_t)cN0 * cD;
    float* y2   = out + (size_t)(cN0 + cN1) * cD;

    // h12 staged in the y0 region of d_out; consumed by pull(y2) before pull(y0)
    uint16_t* h12 = (uint16_t*)y0;

    char* ws = (char*)d_ws;
    size_t o = 0;
    uint16_t* h0      = (uint16_t*)(ws + o); o += (size_t)cN0 * cD * 2;   // 25.6 MB
    uint2*    edges00 = (uint2*)   (ws + o); o += (size_t)cNNZ00 * 8;     // 12.8 MB
    uint2*    edges12 = (uint2*)   (ws + o); o += (size_t)cNNZ12 * 8;     // 1.6 MB
    int*      rs0     = (int*)     (ws + o); o += 400016;
    int*      cur0    = (int*)     (ws + o); o += 400000;
    int*      rs2     = (int*)     (ws + o); o += 200016;
    int*      cur2    = (int*)     (ws + o); o += 200000;
    int*      part0   = (int*)     (ws + o); o += 512;
    int*      part2   = (int*)     (ws + o); o += 512;

    const int nb0 = (cN0 + 1023) / 1024;
    const int nb2 = (cN2 + 1023) / 1024;

    // ---- 1->2 path
    gemm_mfma_kernel<1><<<(cN1 + 127) / 128, 256, 0, stream>>>(x1, W12, h12, out1, cN1);

    hipMemsetAsync(cur2, 0, (size_t)cN2 * 4, stream);
    hist_kernel<<<(cNNZ12 + 255) / 256, 256, 0, stream>>>(r12, cNNZ12, cur2);
    scan_partial<<<nb2, 256, 0, stream>>>(cur2, cN2, part2);
    scan_small<<<1, 256, 0, stream>>>(part2, nb2);
    scan_final<<<nb2, 256, 0, stream>>>(cur2, cN2, part2, rs2, cur2, cNNZ12);
    place_kernel<<<(cNNZ12 + 255) / 256, 256, 0, stream>>>(r12, c12, v12, cNNZ12, cur2, edges12);
    pull_kernel<<<(cN2 + 3) / 4, 256, 0, stream>>>(rs2, edges12, h12, y2, cN2);

    // ---- 0->0 path
    gemm_mfma_kernel<0><<<(cN0 + 127) / 128, 256, 0, stream>>>(x0, W0, h0, nullptr, cN0);

    hipMemsetAsync(cur0, 0, (size_t)cN0 * 4, stream);
    hist_kernel<<<(cNNZ00 + 255) / 256, 256, 0, stream>>>(r00, cNNZ00, cur0);
    scan_partial<<<nb0, 256, 0, stream>>>(cur0, cN0, part0);
    scan_small<<<1, 256, 0, stream>>>(part0, nb0);
    scan_final<<<nb0, 256, 0, stream>>>(cur0, cN0, part0, rs0, cur0, cNNZ00);
    place_kernel<<<(cNNZ00 + 255) / 256, 256, 0, stream>>>(r00, c00, v00, cNNZ00, cur0, edges00);
    pull_kernel<<<(cN0 + 3) / 4, 256, 0, stream>>>(rs0, edges00, h0, y0, cN0);
}

// Round 4
// 533.160 us; speedup vs baseline: 6.4402x; 1.1691x over previous
//
#include <hip/hip_runtime.h>
#include <stdint.h>

#define cN0 100000
#define cN1 150000
#define cN2 50000
#define cNNZ00 1600000
#define cNNZ12 200000
#define cD 128

#define BROWS_LOG 9
#define BROWS 512
#define PBLK_E 8192
#define FCAP 14336

typedef __attribute__((ext_vector_type(8))) short short8;
typedef __attribute__((ext_vector_type(4))) float f32x4;

__device__ __forceinline__ uint16_t f2bf(float f) {
    uint32_t u = __float_as_uint(f);
    u += 0x7fffu + ((u >> 16) & 1u);
    return (uint16_t)(u >> 16);
}
__device__ __forceinline__ float bf2f(uint32_t lo16) {
    return __uint_as_float(lo16 << 16);
}

// ---------------- MFMA GEMM: h[r][c] = bf16( sum_k relu(x[r][k]) * W[k][c] ) --
template<int WRITE_RELU>
__global__ __launch_bounds__(256) void gemm_mfma_kernel(
    const float* __restrict__ x, const float* __restrict__ W,
    uint16_t* __restrict__ h, float* __restrict__ relu_out, int nrows)
{
    __shared__ __align__(16) uint16_t Bpack[cD * cD];   // 32 KB

    const int tid = threadIdx.x;
    for (int i = tid * 4; i < cD * cD; i += 1024) {
        int k = i >> 7, c = i & 127;
        float4 w = *(const float4*)&W[i];
        int kt = k >> 5, q = (k >> 3) & 3, j = k & 7;
        uint16_t b[4] = { f2bf(w.x), f2bf(w.y), f2bf(w.z), f2bf(w.w) };
        #pragma unroll
        for (int t = 0; t < 4; ++t) {
            int cc = c + t, ct = cc >> 4, n = cc & 15;
            Bpack[(((kt * 8 + ct) * 64) + q * 16 + n) * 8 + j] = b[t];
        }
    }
    __syncthreads();

    const int wid = tid >> 6, l = tid & 63;
    const int rb = blockIdx.x * 128 + wid * 32;
    const int m = l & 15, q = l >> 4;
    const int r0 = rb + m, r1 = rb + 16 + m;

    f32x4 acc[2][8];
    #pragma unroll
    for (int rt = 0; rt < 2; ++rt)
        #pragma unroll
        for (int ct = 0; ct < 8; ++ct)
            acc[rt][ct] = (f32x4){0.f, 0.f, 0.f, 0.f};

    for (int kt = 0; kt < 4; ++kt) {
        const int k0 = kt * 32 + q * 8;
        float4 xa0 = make_float4(0.f,0.f,0.f,0.f), xa1 = xa0;
        float4 xb0 = xa0, xb1 = xa0;
        if (r0 < nrows) {
            xa0 = *(const float4*)&x[(size_t)r0 * cD + k0];
            xa1 = *(const float4*)&x[(size_t)r0 * cD + k0 + 4];
        }
        if (r1 < nrows) {
            xb0 = *(const float4*)&x[(size_t)r1 * cD + k0];
            xb1 = *(const float4*)&x[(size_t)r1 * cD + k0 + 4];
        }
        xa0.x=fmaxf(xa0.x,0.f); xa0.y=fmaxf(xa0.y,0.f); xa0.z=fmaxf(xa0.z,0.f); xa0.w=fmaxf(xa0.w,0.f);
        xa1.x=fmaxf(xa1.x,0.f); xa1.y=fmaxf(xa1.y,0.f); xa1.z=fmaxf(xa1.z,0.f); xa1.w=fmaxf(xa1.w,0.f);
        xb0.x=fmaxf(xb0.x,0.f); xb0.y=fmaxf(xb0.y,0.f); xb0.z=fmaxf(xb0.z,0.f); xb0.w=fmaxf(xb0.w,0.f);
        xb1.x=fmaxf(xb1.x,0.f); xb1.y=fmaxf(xb1.y,0.f); xb1.z=fmaxf(xb1.z,0.f); xb1.w=fmaxf(xb1.w,0.f);
        if (WRITE_RELU) {
            if (r0 < nrows) {
                *(float4*)&relu_out[(size_t)r0 * cD + k0]     = xa0;
                *(float4*)&relu_out[(size_t)r0 * cD + k0 + 4] = xa1;
            }
            if (r1 < nrows) {
                *(float4*)&relu_out[(size_t)r1 * cD + k0]     = xb0;
                *(float4*)&relu_out[(size_t)r1 * cD + k0 + 4] = xb1;
            }
        }
        short8 a0, a1;
        a0[0]=(short)f2bf(xa0.x); a0[1]=(short)f2bf(xa0.y); a0[2]=(short)f2bf(xa0.z); a0[3]=(short)f2bf(xa0.w);
        a0[4]=(short)f2bf(xa1.x); a0[5]=(short)f2bf(xa1.y); a0[6]=(short)f2bf(xa1.z); a0[7]=(short)f2bf(xa1.w);
        a1[0]=(short)f2bf(xb0.x); a1[1]=(short)f2bf(xb0.y); a1[2]=(short)f2bf(xb0.z); a1[3]=(short)f2bf(xb0.w);
        a1[4]=(short)f2bf(xb1.x); a1[5]=(short)f2bf(xb1.y); a1[6]=(short)f2bf(xb1.z); a1[7]=(short)f2bf(xb1.w);

        #pragma unroll
        for (int ct = 0; ct < 8; ++ct) {
            short8 bf = *(const short8*)&Bpack[((kt * 8 + ct) * 64 + l) * 8];
            acc[0][ct] = __builtin_amdgcn_mfma_f32_16x16x32_bf16(a0, bf, acc[0][ct], 0, 0, 0);
            acc[1][ct] = __builtin_amdgcn_mfma_f32_16x16x32_bf16(a1, bf, acc[1][ct], 0, 0, 0);
        }
    }

    #pragma unroll
    for (int rt = 0; rt < 2; ++rt) {
        #pragma unroll
        for (int i = 0; i < 4; ++i) {
            int row = rb + rt * 16 + q * 4 + i;
            if (row < nrows) {
                #pragma unroll
                for (int ct = 0; ct < 8; ++ct)
                    h[(size_t)row * cD + ct * 16 + m] = f2bf(acc[rt][ct][i]);
            }
        }
    }
}

// ---------------- CSR build: two-level counting sort ----------------
// Level-0 histogram over 512-row buckets, LDS-aggregated.
__global__ __launch_bounds__(256) void coarse_hist(
    const int* __restrict__ rows, int nnz, int* __restrict__ bcnt, int nb)
{
    __shared__ int sc[256];
    sc[threadIdx.x] = 0;
    __syncthreads();
    for (int i = blockIdx.x * 256 + threadIdx.x; i < nnz; i += gridDim.x * 256)
        atomicAdd(&sc[rows[i] >> BROWS_LOG], 1);
    __syncthreads();
    int t = threadIdx.x;
    if (t < nb && sc[t]) atomicAdd(&bcnt[t], sc[t]);
}

// single-block exclusive scan of bucket counts (nb <= 256)
__global__ __launch_bounds__(256) void bucket_scan(
    const int* __restrict__ bcnt, int nb, int nnz,
    int* __restrict__ bbase, int* __restrict__ bcur)
{
    __shared__ int sm[256];
    int t = threadIdx.x;
    int v = (t < nb) ? bcnt[t] : 0;
    sm[t] = v; __syncthreads();
    for (int o = 1; o < 256; o <<= 1) {
        int x = (t >= o) ? sm[t - o] : 0;
        __syncthreads();
        sm[t] += x;
        __syncthreads();
    }
    int ex = sm[t] - v;
    if (t < nb) { bbase[t] = ex; bcur[t] = ex; }
    if (t == 0) bbase[nb] = nnz;
}

// Partition 8192 edges/block into bucket-contiguous runs via LDS staging.
// Output edge: .x = (row_local << 20) | col, .y = bits(val)
__global__ __launch_bounds__(256) void partition_kernel(
    const int* __restrict__ rows, const int* __restrict__ cols,
    const float* __restrict__ vals, int nnz, int nb,
    int* __restrict__ bcur, uint2* __restrict__ out)
{
    __shared__ uint2   sedge[PBLK_E];    // 64 KB
    __shared__ uint8_t sbkt[PBLK_E];     // 8 KB
    __shared__ int lcount[256], loffset[256], lcur[256], gbase[256];
    const int tid = threadIdx.x;
    const int base = blockIdx.x * PBLK_E;
    const int count = min(PBLK_E, nnz - base);

    lcount[tid] = 0;
    __syncthreads();
    for (int i = tid; i < count; i += 256)
        atomicAdd(&lcount[rows[base + i] >> BROWS_LOG], 1);
    __syncthreads();

    int v = lcount[tid];
    loffset[tid] = v;
    __syncthreads();
    for (int o = 1; o < 256; o <<= 1) {
        int x = (tid >= o) ? loffset[tid - o] : 0;
        __syncthreads();
        loffset[tid] += x;
        __syncthreads();
    }
    int ex = loffset[tid] - v;
    __syncthreads();
    loffset[tid] = ex;
    lcur[tid] = ex;
    if (tid < nb && v > 0) gbase[tid] = atomicAdd(&bcur[tid], v);
    __syncthreads();

    for (int i = tid; i < count; i += 256) {
        int r = rows[base + i];
        uint32_t c = (uint32_t)cols[base + i];
        float w = vals[base + i];
        int b = r >> BROWS_LOG;
        int pos = atomicAdd(&lcur[b], 1);
        sedge[pos] = make_uint2(((uint32_t)(r & (BROWS - 1)) << 20) | c, __float_as_uint(w));
        sbkt[pos] = (uint8_t)b;
    }
    __syncthreads();

    for (int i = tid; i < count; i += 256) {
        int b = sbkt[i];
        out[gbase[b] + (i - loffset[b])] = sedge[i];
    }
}

// One block per bucket: stage bucket in LDS, counting-sort by row (in place),
// emit global row_start.
__global__ __launch_bounds__(256) void fine_place_kernel(
    const int* __restrict__ bbase, uint2* __restrict__ edges,
    int* __restrict__ rs, int n, int nnz)
{
    __shared__ uint2 sedge[FCAP];    // 112 KB
    __shared__ int rcnt[BROWS];      // counts -> cursors
    __shared__ int psc[256];         // pair-sum scan scratch
    const int b = blockIdx.x, tid = threadIdx.x;
    const int s = bbase[b], e = bbase[b + 1];
    const int count = e - s;
    const int lo = b << BROWS_LOG;
    const int nr = min(BROWS, n - lo);

    for (int r = tid; r < BROWS; r += 256) rcnt[r] = 0;
    __syncthreads();
    for (int i = tid; i < count && i < FCAP; i += 256) {
        uint2 ed = edges[s + i];
        sedge[i] = ed;
        atomicAdd(&rcnt[ed.x >> 20], 1);
    }
    __syncthreads();

    int c0 = rcnt[2 * tid], c1 = rcnt[2 * tid + 1];
    int sum = c0 + c1;
    psc[tid] = sum;
    __syncthreads();
    for (int o = 1; o < 256; o <<= 1) {
        int x = (tid >= o) ? psc[tid - o] : 0;
        __syncthreads();
        psc[tid] += x;
        __syncthreads();
    }
    int pexcl = psc[tid] - sum;
    int e0 = pexcl, e1 = pexcl + c0;
    if (2 * tid < nr)     rs[lo + 2 * tid]     = s + e0;
    if (2 * tid + 1 < nr) rs[lo + 2 * tid + 1] = s + e1;
    __syncthreads();
    rcnt[2 * tid] = e0;
    rcnt[2 * tid + 1] = e1;
    __syncthreads();

    for (int i = tid; i < count && i < FCAP; i += 256) {
        uint2 ed = sedge[i];
        int rl = ed.x >> 20;
        int pos = atomicAdd(&rcnt[rl], 1);
        edges[s + pos] = make_uint2(ed.x & 0xFFFFFu, ed.y);
    }
    if (b == 0 && tid == 0) rs[n] = nnz;
}

// ---------------- Pull: y[r] = relu(sum_e val*h[col]) , one wave per row -----
__global__ __launch_bounds__(256) void pull_kernel(
    const int* __restrict__ row_start, const uint2* __restrict__ edges,
    const uint16_t* __restrict__ h, float* __restrict__ y, int nrows)
{
    int w = (blockIdx.x * 256 + threadIdx.x) >> 6;
    int l = threadIdx.x & 63;
    if (w >= nrows) return;
    int s = row_start[w], e = row_start[w + 1];
    float a0 = 0.f, a1 = 0.f;
    int i = s;
    for (; i + 3 < e; i += 4) {
        uint2 e0 = edges[i], e1 = edges[i + 1], e2 = edges[i + 2], e3 = edges[i + 3];
        uint32_t p0 = *(const uint32_t*)&h[(size_t)e0.x * cD + l * 2];
        uint32_t p1 = *(const uint32_t*)&h[(size_t)e1.x * cD + l * 2];
        uint32_t p2 = *(const uint32_t*)&h[(size_t)e2.x * cD + l * 2];
        uint32_t p3 = *(const uint32_t*)&h[(size_t)e3.x * cD + l * 2];
        float v0 = __uint_as_float(e0.y), v1 = __uint_as_float(e1.y);
        float v2 = __uint_as_float(e2.y), v3 = __uint_as_float(e3.y);
        a0 = fmaf(v0, bf2f(p0 & 0xffffu), a0); a1 = fmaf(v0, bf2f(p0 >> 16), a1);
        a0 = fmaf(v1, bf2f(p1 & 0xffffu), a0); a1 = fmaf(v1, bf2f(p1 >> 16), a1);
        a0 = fmaf(v2, bf2f(p2 & 0xffffu), a0); a1 = fmaf(v2, bf2f(p2 >> 16), a1);
        a0 = fmaf(v3, bf2f(p3 & 0xffffu), a0); a1 = fmaf(v3, bf2f(p3 >> 16), a1);
    }
    for (; i < e; ++i) {
        uint2 ed = edges[i];
        uint32_t p = *(const uint32_t*)&h[(size_t)ed.x * cD + l * 2];
        float v = __uint_as_float(ed.y);
        a0 = fmaf(v, bf2f(p & 0xffffu), a0);
        a1 = fmaf(v, bf2f(p >> 16), a1);
    }
    *(float2*)&y[(size_t)w * cD + l * 2] = make_float2(fmaxf(a0, 0.f), fmaxf(a1, 0.f));
}

extern "C" void kernel_launch(void* const* d_in, const int* in_sizes, int n_in,
                              void* d_out, int out_size, void* d_ws, size_t ws_size,
                              hipStream_t stream) {
    const float* x0  = (const float*)d_in[0];
    const float* x1  = (const float*)d_in[1];
    const int*   r00 = (const int*)d_in[2];
    const int*   c00 = (const int*)d_in[3];
    const float* v00 = (const float*)d_in[4];
    const int*   r12 = (const int*)d_in[5];
    const int*   c12 = (const int*)d_in[6];
    const float* v12 = (const float*)d_in[7];
    const float* W0  = (const float*)d_in[8];
    const float* W12 = (const float*)d_in[9];

    float* out  = (float*)d_out;
    float* y0   = out;
    float* out1 = out + (size_t)cN0 * cD;
    float* y2   = out + (size_t)(cN0 + cN1) * cD;

    // h12 staged in the y0 region of d_out; consumed by pull(y2) before pull(y0)
    uint16_t* h12 = (uint16_t*)y0;

    const int NB0 = (cN0 + BROWS - 1) / BROWS;   // 196
    const int NB2 = (cN2 + BROWS - 1) / BROWS;   // 98

    char* ws = (char*)d_ws;
    size_t o = 0;
    uint16_t* h0      = (uint16_t*)(ws + o); o += (size_t)cN0 * cD * 2;   // 25.6 MB
    uint2*    edges00 = (uint2*)   (ws + o); o += (size_t)cNNZ00 * 8;     // 12.8 MB
    uint2*    edges12 = (uint2*)   (ws + o); o += (size_t)cNNZ12 * 8;     // 1.6 MB
    int*      rs0     = (int*)     (ws + o); o += ((size_t)cN0 + 1) * 4;
    int*      rs2     = (int*)     (ws + o); o += ((size_t)cN2 + 1) * 4;
    int*      bcnt0   = (int*)     (ws + o); o += 256 * 4;
    int*      bbase0  = (int*)     (ws + o); o += 257 * 4;
    int*      bcur0   = (int*)     (ws + o); o += 256 * 4;
    int*      bcnt2   = (int*)     (ws + o); o += 256 * 4;
    int*      bbase2  = (int*)     (ws + o); o += 257 * 4;
    int*      bcur2   = (int*)     (ws + o); o += 256 * 4;

    // ---- 1->2 path
    gemm_mfma_kernel<1><<<(cN1 + 127) / 128, 256, 0, stream>>>(x1, W12, h12, out1, cN1);

    hipMemsetAsync(bcnt2, 0, 256 * 4, stream);
    coarse_hist<<<128, 256, 0, stream>>>(r12, cNNZ12, bcnt2, NB2);
    bucket_scan<<<1, 256, 0, stream>>>(bcnt2, NB2, cNNZ12, bbase2, bcur2);
    partition_kernel<<<(cNNZ12 + PBLK_E - 1) / PBLK_E, 256, 0, stream>>>(
        r12, c12, v12, cNNZ12, NB2, bcur2, edges12);
    fine_place_kernel<<<NB2, 256, 0, stream>>>(bbase2, edges12, rs2, cN2, cNNZ12);
    pull_kernel<<<(cN2 + 3) / 4, 256, 0, stream>>>(rs2, edges12, h12, y2, cN2);

    // ---- 0->0 path
    gemm_mfma_kernel<0><<<(cN0 + 127) / 128, 256, 0, stream>>>(x0, W0, h0, nullptr, cN0);

    hipMemsetAsync(bcnt0, 0, 256 * 4, stream);
    coarse_hist<<<512, 256, 0, stream>>>(r00, cNNZ00, bcnt0, NB0);
    bucket_scan<<<1, 256, 0, stream>>>(bcnt0, NB0, cNNZ00, bbase0, bcur0);
    partition_kernel<<<(cNNZ00 + PBLK_E - 1) / PBLK_E, 256, 0, stream>>>(
        r00, c00, v00, cNNZ00, NB0, bcur0, edges00);
    fine_place_kernel<<<NB0, 256, 0, stream>>>(bbase0, edges00, rs0, cN0, cNNZ00);
    pull_kernel<<<(cN0 + 3) / 4, 256, 0, stream>>>(rs0, edges00, h0, y0, cN0);
}